// Round 1
// baseline (460.760 us; speedup 1.0000x reference)
//
#include <hip/hip_runtime.h>

#define NB 4
#define NT 2048
#define DM 1024
#define DH 64

// ---------------------------------------------------------------------------
// Kernel 1: QKV projection. One block per (b,t) row.
// Stage x-row (4KB) in LDS; wave 0 -> Q cols, wave 1 -> K cols, wave 2 -> V.
// W reads coalesced (lane = output col, consecutive addresses).
// ---------------------------------------------------------------------------
__global__ __launch_bounds__(256) void qkv_kernel(
    const float* __restrict__ x,
    const float* __restrict__ WQ,
    const float* __restrict__ WK,
    const float* __restrict__ WV,
    float* __restrict__ Q, float* __restrict__ K, float* __restrict__ V)
{
    __shared__ float xs[DM];
    const int row = blockIdx.x;
    const float* xr = x + (size_t)row * DM;
    for (int m = threadIdx.x * 4; m < DM; m += 256 * 4)
        *(float4*)&xs[m] = *(const float4*)&xr[m];
    __syncthreads();

    const int col   = threadIdx.x & 63;
    const int which = threadIdx.x >> 6;   // 0=Q, 1=K, 2=V, 3=idle
    if (which >= 3) return;
    const float* __restrict__ W = (which == 0) ? WQ : (which == 1) ? WK : WV;

    float a0 = 0.f, a1 = 0.f, a2 = 0.f, a3 = 0.f;
    #pragma unroll 8
    for (int m = 0; m < DM; m += 4) {
        float4 xv = *(const float4*)&xs[m];
        a0 += xv.x * W[(m + 0) * DH + col];
        a1 += xv.y * W[(m + 1) * DH + col];
        a2 += xv.z * W[(m + 2) * DH + col];
        a3 += xv.w * W[(m + 3) * DH + col];
    }
    float* out = (which == 0) ? Q : (which == 1) ? K : V;
    out[(size_t)row * DH + col] = (a0 + a1) + (a2 + a3);
}

// ---------------------------------------------------------------------------
// Kernel 2: causal flash attention. Block = 4 waves = 4 query rows.
// K/V 64-row tiles staged in LDS (row stride 68 floats: float4 reads run at
// full LDS BW, scalar V reads conflict-free). Online softmax per wave.
// QK phase: lane = key index within tile. PV phase: lane = head dim.
// ---------------------------------------------------------------------------
__global__ __launch_bounds__(256) void attn_kernel(
    const float* __restrict__ Q, const float* __restrict__ K,
    const float* __restrict__ V, float* __restrict__ O)
{
    __shared__ float ks[64][68];
    __shared__ float vs[64][68];
    __shared__ float qs[4][64];

    const int lane = threadIdx.x & 63;
    const int wave = threadIdx.x >> 6;
    const int b    = blockIdx.y;
    const int i0   = blockIdx.x * 4;       // first query row of block
    const int i    = i0 + wave;            // this wave's query row

    const float* Qb = Q + (size_t)b * NT * DH;
    const float* Kb = K + (size_t)b * NT * DH;
    const float* Vb = V + (size_t)b * NT * DH;

    // each wave stages its own q row (same-wave producer/consumer, no barrier)
    qs[wave][lane] = Qb[(size_t)i * DH + lane];

    float m_run = -INFINITY;
    float l_run = 0.f;
    float o     = 0.f;                      // lane holds o[d = lane]

    // i0 % 64 <= 60, so all 4 rows share the same tile count (no divergence)
    const int ntiles = i0 / 64 + 1;
    for (int t = 0; t < ntiles; ++t) {
        const int j0 = t * 64;
        __syncthreads();                    // LDS reuse guard

        // stage K,V tile: thread -> (row jj, 16-float chunk c0), coalesced
        {
            const int jj = threadIdx.x >> 2;
            const int c0 = (threadIdx.x & 3) * 16;
            const float4* ksrc = (const float4*)&Kb[(size_t)(j0 + jj) * DH + c0];
            const float4* vsrc = (const float4*)&Vb[(size_t)(j0 + jj) * DH + c0];
            float4* kdst = (float4*)&ks[jj][c0];
            float4* vdst = (float4*)&vs[jj][c0];
            #pragma unroll
            for (int c = 0; c < 4; ++c) { kdst[c] = ksrc[c]; vdst[c] = vsrc[c]; }
        }
        __syncthreads();

        // ---- QK^T: lane l -> key j0+l ----
        const int j = j0 + lane;
        float s;
        if (j <= i) {
            float acc = 0.f;
            const float4* kr = (const float4*)&ks[lane][0];
            const float4* qr = (const float4*)&qs[wave][0];
            #pragma unroll
            for (int c = 0; c < 16; ++c) {
                float4 kv = kr[c];
                float4 qv = qr[c];
                acc += kv.x * qv.x + kv.y * qv.y + kv.z * qv.z + kv.w * qv.w;
            }
            s = acc * 0.125f;               // 1/sqrt(64)
        } else {
            s = -1e30f;                     // causal mask
        }

        // ---- online softmax (wave reductions) ----
        float mx = s;
        #pragma unroll
        for (int off = 32; off; off >>= 1)
            mx = fmaxf(mx, __shfl_xor(mx, off));
        const float m_new = fmaxf(m_run, mx);
        const float p = __expf(s - m_new);  // masked lanes underflow to 0
        float psum = p;
        #pragma unroll
        for (int off = 32; off; off >>= 1)
            psum += __shfl_xor(psum, off);
        const float alpha = __expf(m_run - m_new);  // first tile: exp(-inf)=0
        l_run = l_run * alpha + psum;
        o *= alpha;

        // ---- PV: lane = head dim, broadcast p_j via shuffle ----
        #pragma unroll 8
        for (int jj = 0; jj < 64; ++jj) {
            float pj = __shfl(p, jj);
            o += pj * vs[jj][lane];
        }
        m_run = m_new;
    }

    O[((size_t)b * NT + i) * DH + lane] = o / l_run;
}

extern "C" void kernel_launch(void* const* d_in, const int* in_sizes, int n_in,
                              void* d_out, int out_size, void* d_ws, size_t ws_size,
                              hipStream_t stream) {
    const float* x  = (const float*)d_in[0];
    const float* WQ = (const float*)d_in[1];
    const float* WK = (const float*)d_in[2];
    const float* WV = (const float*)d_in[3];
    float* out = (float*)d_out;

    float* Q = (float*)d_ws;
    float* K = Q + (size_t)NB * NT * DH;
    float* V = K + (size_t)NB * NT * DH;

    qkv_kernel<<<NB * NT, 256, 0, stream>>>(x, WQ, WK, WV, Q, K, V);
    attn_kernel<<<dim3(NT / 4, NB), 256, 0, stream>>>(Q, K, V, out);
}

// Round 2
// 140.741 us; speedup vs baseline: 3.2738x; 3.2738x over previous
//
#include <hip/hip_runtime.h>
#include <hip/hip_bf16.h>

#define NB 4
#define NT 2048
#define DM 1024
#define DH 64

typedef __attribute__((ext_vector_type(8))) short bf16x8;
typedef __attribute__((ext_vector_type(4))) float f32x4;
typedef unsigned short u16;
typedef unsigned int u32;

static __device__ __forceinline__ u16 f2bf(float f) {
    u32 u = __builtin_bit_cast(u32, f);
    return (u16)((u + 0x7FFF + ((u >> 16) & 1)) >> 16);   // RNE
}
static __device__ __forceinline__ float bf2f(u16 h) {
    return __builtin_bit_cast(float, (u32)h << 16);
}

// ---------------------------------------------------------------------------
// Wt[which][d][k] bf16  <-  W[k][d] fp32   (B-operand wants k-contiguous rows)
// ---------------------------------------------------------------------------
__global__ __launch_bounds__(256) void wt_conv(
    const float* __restrict__ WQ, const float* __restrict__ WK,
    const float* __restrict__ WV, u16* __restrict__ wt)
{
    int idx = blockIdx.x * 256 + threadIdx.x;      // 0..196607
    int which = idx >> 16;
    int rem = idx & 0xFFFF;
    int d = rem >> 10, k = rem & 1023;
    const float* W = (which == 0) ? WQ : (which == 1) ? WK : WV;
    wt[idx] = f2bf(W[k * DH + d]);                 // wt write coalesced in k
}

// ---------------------------------------------------------------------------
// QKV GEMM: M=8192, K=1024, N=192 (Q|K|V). BM=64, 4 waves (16 rows each).
// x fp32 -> bf16 conversion fused into swizzled LDS staging.
// Q scaled by 1/8 at store. V stored transposed: Vt[b][d][t].
// ---------------------------------------------------------------------------
__global__ __launch_bounds__(256) void qkv_gemm(
    const float* __restrict__ x, const u16* __restrict__ wt,
    u16* __restrict__ Qb, u16* __restrict__ Kb, u16* __restrict__ Vt)
{
    __shared__ u16 xs[64 * 64];
    const int tid = threadIdx.x;
    const int lane = tid & 63, w = tid >> 6;
    const int l15 = lane & 15, g = lane >> 4;
    const int row0 = blockIdx.x * 64;

    f32x4 acc[12];
    #pragma unroll
    for (int i = 0; i < 12; ++i) acc[i] = {0.f, 0.f, 0.f, 0.f};

    for (int kt = 0; kt < 16; ++kt) {
        __syncthreads();
        // stage x tile [64 rows][64 k] as bf16, XOR-swizzled
        #pragma unroll
        for (int it = 0; it < 2; ++it) {
            int id = tid + it * 256;               // 0..511
            int r = id >> 3, c = id & 7;           // row, 8-elem chunk
            const float* src = x + (size_t)(row0 + r) * DM + kt * 64 + c * 8;
            float4 f0 = *(const float4*)src;
            float4 f1 = *(const float4*)(src + 4);
            u16 tmp[8] = {f2bf(f0.x), f2bf(f0.y), f2bf(f0.z), f2bf(f0.w),
                          f2bf(f1.x), f2bf(f1.y), f2bf(f1.z), f2bf(f1.w)};
            u32 addr = (u32)((r * 128 + c * 16) ^ ((r & 7) << 4));
            *(uint4*)((char*)xs + addr) = *(uint4*)tmp;
        }
        __syncthreads();
        #pragma unroll
        for (int ks = 0; ks < 2; ++ks) {
            int arow = w * 16 + l15;
            u32 aaddr = (u32)((arow * 128 + (ks * 32 + g * 8) * 2) ^ ((arow & 7) << 4));
            bf16x8 afrag = *(bf16x8*)((char*)xs + aaddr);
            #pragma unroll
            for (int nt = 0; nt < 12; ++nt) {
                const u16* bsrc = wt + (nt >> 2) * 65536
                                + ((nt & 3) * 16 + l15) * 1024
                                + kt * 64 + ks * 32 + g * 8;
                bf16x8 bfrag = *(const bf16x8*)bsrc;
                acc[nt] = __builtin_amdgcn_mfma_f32_16x16x32_bf16(afrag, bfrag, acc[nt], 0, 0, 0);
            }
        }
    }
    // epilogue: C layout col = l15, row = g*4 + reg
    #pragma unroll
    for (int nt = 0; nt < 12; ++nt) {
        int sel = nt >> 2, dcol = (nt & 3) * 16 + l15;
        #pragma unroll
        for (int r = 0; r < 4; ++r) {
            int row = row0 + w * 16 + g * 4 + r;
            float v = acc[nt][r];
            if (sel == 0)      Qb[(size_t)row * DH + dcol] = f2bf(v * 0.125f);
            else if (sel == 1) Kb[(size_t)row * DH + dcol] = f2bf(v);
            else {
                int b = row >> 11, t = row & 2047;
                Vt[(size_t)b * DH * NT + (size_t)dcol * NT + t] = f2bf(v);
            }
        }
    }
}

// ---------------------------------------------------------------------------
// Flash attention, bf16 MFMA. Block = 4 waves x 16 q-rows (QBLK=64).
// grid.x encodes (qb, kv-half): each block does half the causal KV range,
// writes unnormalized partials (bf16 O + f32 m,l); merge kernel combines.
// ---------------------------------------------------------------------------
__global__ __launch_bounds__(256) void attn(
    const u16* __restrict__ Qb, const u16* __restrict__ Kb,
    const u16* __restrict__ Vt, u16* __restrict__ pO, float* __restrict__ pml)
{
    __shared__ u16 k_lds[64 * 64];
    __shared__ u16 v_lds[64 * 64];
    __shared__ u16 p_lds[4][16 * 80];

    const int tid = threadIdx.x, lane = tid & 63, w = tid >> 6;
    const int l15 = lane & 15, g = lane >> 4;
    const int b = blockIdx.y;
    const int qb = blockIdx.x >> 1, s = blockIdx.x & 1;
    const int q0 = qb * 64;
    const int ntot = qb + 1, h = ntot >> 1;
    const int t0 = s ? h : 0, t1 = s ? ntot : h;

    // Q fragments (A layout: row = l15, k = g*8 + ks*32), 1/8 pre-scaled
    const u16* Qg = Qb + ((size_t)b * NT + q0 + w * 16) * DH;
    bf16x8 qf[2];
    qf[0] = *(const bf16x8*)(Qg + l15 * DH + g * 8);
    qf[1] = *(const bf16x8*)(Qg + l15 * DH + 32 + g * 8);

    float m_run[4], l_run[4];
    f32x4 oacc[4];
    #pragma unroll
    for (int r = 0; r < 4; ++r) { m_run[r] = -INFINITY; l_run[r] = 0.f; }
    #pragma unroll
    for (int nt = 0; nt < 4; ++nt) oacc[nt] = {0.f, 0.f, 0.f, 0.f};

    const u16* Kg = Kb + (size_t)b * NT * DH;
    const u16* Vg = Vt + (size_t)b * DH * NT;

    for (int t = t0; t < t1; ++t) {
        const int j0 = t * 64;
        __syncthreads();
        // stage K [j][d] and Vt [d][j] tiles, XOR-swizzled
        #pragma unroll
        for (int it = 0; it < 2; ++it) {
            int id = tid + it * 256;
            int r = id >> 3, c = id & 7;
            uint4 kv = *(const uint4*)(Kg + (size_t)(j0 + r) * DH + c * 8);
            *(uint4*)((char*)k_lds + ((r * 128 + c * 16) ^ ((r & 7) << 4))) = kv;
            uint4 vv = *(const uint4*)(Vg + (size_t)r * NT + j0 + c * 8);
            *(uint4*)((char*)v_lds + ((r * 128 + c * 16) ^ ((r & 7) << 4))) = vv;
        }
        __syncthreads();

        // ---- QK^T: S[16 q x 64 j] per wave ----
        f32x4 sacc[4];
        #pragma unroll
        for (int nt = 0; nt < 4; ++nt) sacc[nt] = {0.f, 0.f, 0.f, 0.f};
        #pragma unroll
        for (int ks = 0; ks < 2; ++ks) {
            #pragma unroll
            for (int nt = 0; nt < 4; ++nt) {
                int jrow = nt * 16 + l15;
                u32 baddr = (u32)((jrow * 128 + (ks * 32 + g * 8) * 2) ^ ((jrow & 7) << 4));
                bf16x8 bf = *(bf16x8*)((char*)k_lds + baddr);
                sacc[nt] = __builtin_amdgcn_mfma_f32_16x16x32_bf16(qf[ks], bf, sacc[nt], 0, 0, 0);
            }
        }
        // causal mask only on the diagonal tile
        if (t == qb) {
            #pragma unroll
            for (int nt = 0; nt < 4; ++nt) {
                int j_local = nt * 16 + l15;
                #pragma unroll
                for (int r = 0; r < 4; ++r) {
                    int q_local = w * 16 + g * 4 + r;
                    if (j_local > q_local) sacc[nt][r] = -1e30f;
                }
            }
        }
        // ---- online softmax (rows live in 16-lane groups) ----
        float p[4][4];
        #pragma unroll
        for (int r = 0; r < 4; ++r) {
            float mx = fmaxf(fmaxf(sacc[0][r], sacc[1][r]), fmaxf(sacc[2][r], sacc[3][r]));
            mx = fmaxf(mx, __shfl_xor(mx, 1));
            mx = fmaxf(mx, __shfl_xor(mx, 2));
            mx = fmaxf(mx, __shfl_xor(mx, 4));
            mx = fmaxf(mx, __shfl_xor(mx, 8));
            float m_new = fmaxf(m_run[r], mx);
            float alpha = __expf(m_run[r] - m_new);
            float ps = 0.f;
            #pragma unroll
            for (int nt = 0; nt < 4; ++nt) {
                float pv = __expf(sacc[nt][r] - m_new);
                p[nt][r] = pv; ps += pv;
            }
            ps += __shfl_xor(ps, 1); ps += __shfl_xor(ps, 2);
            ps += __shfl_xor(ps, 4); ps += __shfl_xor(ps, 8);
            l_run[r] = l_run[r] * alpha + ps;
            m_run[r] = m_new;
            #pragma unroll
            for (int nt = 0; nt < 4; ++nt) oacc[nt][r] *= alpha;
        }
        // ---- P -> per-wave LDS (stride 80), re-read in A layout ----
        u16* pw = p_lds[w];
        #pragma unroll
        for (int r = 0; r < 4; ++r) {
            int qrow = g * 4 + r;
            #pragma unroll
            for (int nt = 0; nt < 4; ++nt)
                pw[qrow * 80 + nt * 16 + l15] = f2bf(p[nt][r]);
        }
        // ---- PV: O[16 q x 64 d] += P[16 x 64] @ V[64 x 64] ----
        #pragma unroll
        for (int ks = 0; ks < 2; ++ks) {
            bf16x8 pa = *(bf16x8*)((char*)pw + (l15 * 160 + (ks * 32 + g * 8) * 2));
            #pragma unroll
            for (int nt = 0; nt < 4; ++nt) {
                int drow = nt * 16 + l15;
                u32 baddr = (u32)((drow * 128 + (ks * 32 + g * 8) * 2) ^ ((drow & 7) << 4));
                bf16x8 vf = *(bf16x8*)((char*)v_lds + baddr);
                oacc[nt] = __builtin_amdgcn_mfma_f32_16x16x32_bf16(pa, vf, oacc[nt], 0, 0, 0);
            }
        }
    }

    // write partials (unnormalized O in bf16, per-row m,l in f32)
    const int pidx = (b * 32 + qb) * 2 + s;
    u16* Op = pO + (size_t)pidx * 64 * 64;
    #pragma unroll
    for (int nt = 0; nt < 4; ++nt)
        #pragma unroll
        for (int r = 0; r < 4; ++r)
            Op[(w * 16 + g * 4 + r) * 64 + nt * 16 + l15] = f2bf(oacc[nt][r]);
    if (l15 == 0) {
        float* mlp = pml + (size_t)pidx * 128;
        #pragma unroll
        for (int r = 0; r < 4; ++r) {
            int row = w * 16 + g * 4 + r;
            mlp[row * 2]     = m_run[r];
            mlp[row * 2 + 1] = l_run[r];
        }
    }
}

// ---------------------------------------------------------------------------
// Merge the two KV-half partials per q-block row; write fp32 output.
// ---------------------------------------------------------------------------
__global__ __launch_bounds__(256) void merge(
    const u16* __restrict__ pO, const float* __restrict__ pml,
    float* __restrict__ out)
{
    int idx = blockIdx.x * 256 + threadIdx.x;   // row*64 + d
    int row = idx >> 6, d = idx & 63;
    int b = row >> 11, q = row & 2047;
    int qb = q >> 6, rl = q & 63;
    int base = (b * 32 + qb) * 2;
    const float* ml0 = pml + (size_t)base * 128 + rl * 2;
    const float* ml1 = pml + (size_t)(base + 1) * 128 + rl * 2;
    float m0 = ml0[0], l0 = ml0[1];
    float m1 = ml1[0], l1 = ml1[1];
    float m = fmaxf(m0, m1);
    float w0 = __expf(m0 - m), w1 = __expf(m1 - m);
    float o0 = bf2f(pO[(size_t)base * 4096 + rl * 64 + d]);
    float o1 = bf2f(pO[(size_t)(base + 1) * 4096 + rl * 64 + d]);
    out[idx] = (o0 * w0 + o1 * w1) / (l0 * w0 + l1 * w1);
}

extern "C" void kernel_launch(void* const* d_in, const int* in_sizes, int n_in,
                              void* d_out, int out_size, void* d_ws, size_t ws_size,
                              hipStream_t stream) {
    const float* x  = (const float*)d_in[0];
    const float* WQ = (const float*)d_in[1];
    const float* WK = (const float*)d_in[2];
    const float* WV = (const float*)d_in[3];
    float* out = (float*)d_out;

    char* ws = (char*)d_ws;
    u16*   Qb  = (u16*)(ws);                       // 1 MB
    u16*   Kb  = (u16*)(ws + 1048576);             // 1 MB
    u16*   Vt  = (u16*)(ws + 2097152);             // 1 MB
    u16*   Wt  = (u16*)(ws + 3145728);             // 384 KB
    u16*   pO  = (u16*)(ws + 3538944);             // 2 MB
    float* pml = (float*)(ws + 5636096);           // 128 KB -> total 5.5 MB

    wt_conv<<<768, 256, 0, stream>>>(WQ, WK, WV, Wt);
    qkv_gemm<<<128, 256, 0, stream>>>(x, Wt, Qb, Kb, Vt);
    attn<<<dim3(64, NB), 256, 0, stream>>>(Qb, Kb, Vt, pO, pml);
    merge<<<2048, 256, 0, stream>>>(pO, pml, out);
}

// Round 3
// 52.225 us; speedup vs baseline: 8.8226x; 2.6949x over previous
//
#include <hip/hip_runtime.h>
#include <hip/hip_bf16.h>

#define NB 4
#define NT 2048
#define DM 1024
#define DH 64

typedef __attribute__((ext_vector_type(8))) short bf16x8;
typedef __attribute__((ext_vector_type(4))) float f32x4;
typedef unsigned short u16;
typedef unsigned int u32;

static __device__ __forceinline__ u16 f2b(float f) {
    __hip_bfloat16 h = __float2bfloat16(f);
    return __builtin_bit_cast(u16, h);
}
static __device__ __forceinline__ float b2f(u16 h) {
    return __builtin_bit_cast(float, (u32)h << 16);
}
// global -> LDS DMA, 16B per lane. lds ptr must be wave-uniform (HW adds lane*16).
static __device__ __forceinline__ void gld16(const void* g, void* l) {
    __builtin_amdgcn_global_load_lds((const __attribute__((address_space(1))) void*)g,
                                     (__attribute__((address_space(3))) void*)l, 16, 0, 0);
}

// ---------------------------------------------------------------------------
// Wt[which][d][k] bf16 <- W[k][d] fp32, via LDS transpose (coalesced R & W).
// grid (16, 3)
// ---------------------------------------------------------------------------
__global__ __launch_bounds__(256) void wt_conv(
    const float* __restrict__ WQ, const float* __restrict__ WK,
    const float* __restrict__ WV, u16* __restrict__ wt)
{
    __shared__ u16 tl[64][68];
    const int which = blockIdx.y, kt = blockIdx.x;
    const float* W = (which == 0) ? WQ : (which == 1) ? WK : WV;
    #pragma unroll
    for (int i = 0; i < 4; ++i) {
        int r = (threadIdx.x >> 4) + i * 16;         // k-local
        int c = (threadIdx.x & 15) * 4;              // d
        float4 v = *(const float4*)&W[(size_t)(kt * 64 + r) * DH + c];
        tl[r][c] = f2b(v.x); tl[r][c + 1] = f2b(v.y);
        tl[r][c + 2] = f2b(v.z); tl[r][c + 3] = f2b(v.w);
    }
    __syncthreads();
    int d = threadIdx.x >> 2, kc = (threadIdx.x & 3) * 16;
    u16 buf[16];
    #pragma unroll
    for (int j = 0; j < 16; ++j) buf[j] = tl[kc + j][d];
    u16* dst = wt + which * 65536 + d * 1024 + kt * 64 + kc;
    *(uint4*)dst = *(uint4*)&buf[0];
    *(uint4*)(dst + 8) = *(uint4*)&buf[8];
}

// ---------------------------------------------------------------------------
// QKV GEMM. grid (128, 3): 64-row tile x one of Q/K/V. 4 waves (16 rows each).
// x staged fp32 via global_load_lds (pre-swizzled source), converted to bf16
// at A-frag build. W tile staged bf16 via global_load_lds (pre-swizzled).
// ---------------------------------------------------------------------------
__global__ __launch_bounds__(256) void qkv_gemm(
    const float* __restrict__ x, const u16* __restrict__ wt,
    u16* __restrict__ Qb, u16* __restrict__ Kb, u16* __restrict__ Vt)
{
    __shared__ float xs[64 * 64];     // 16 KB fp32, swizzle ^((r&7)<<5)
    __shared__ u16 wsm[64 * 64];      // 8 KB bf16,  swizzle ^((r&7)<<4)
    const int tid = threadIdx.x, lane = tid & 63, w = tid >> 6;
    const int l15 = lane & 15, g = lane >> 4;
    const int row0 = blockIdx.x * 64;
    const int which = blockIdx.y;
    const u16* Wg = wt + which * 65536;

    f32x4 acc[4];
    #pragma unroll
    for (int i = 0; i < 4; ++i) acc[i] = {0.f, 0.f, 0.f, 0.f};

    for (int kt = 0; kt < 16; ++kt) {
        __syncthreads();
        // stage x tile [64 r][64 k] fp32: lane's dest D -> source col cs
        #pragma unroll
        for (int i = 0; i < 4; ++i) {
            u32 D = (u32)(w * 4096 + i * 1024 + lane * 16);
            u32 r = D >> 8, c = D & 255;
            u32 cs = c ^ ((r & 7) << 5);
            gld16(x + (size_t)(row0 + r) * DM + kt * 64 + (cs >> 2),
                  (char*)xs + w * 4096 + i * 1024);
        }
        // stage W tile [64 d][64 k] bf16
        #pragma unroll
        for (int i = 0; i < 2; ++i) {
            u32 D = (u32)(w * 2048 + i * 1024 + lane * 16);
            u32 r = D >> 7, c = D & 127;
            u32 cs = c ^ ((r & 7) << 4);
            gld16(Wg + (size_t)r * 1024 + kt * 64 + (cs >> 1),
                  (char*)wsm + w * 2048 + i * 1024);
        }
        __syncthreads();

        const int arow = w * 16 + l15;
        #pragma unroll
        for (int ks = 0; ks < 2; ++ks) {
            u32 abase = (u32)(arow * 256 + ks * 128 + g * 32);
            float af[8];
            *(f32x4*)&af[0] = *(const f32x4*)((const char*)xs + (abase ^ ((arow & 7) << 5)));
            *(f32x4*)&af[4] = *(const f32x4*)((const char*)xs + ((abase + 16) ^ ((arow & 7) << 5)));
            bf16x8 afrag;
            #pragma unroll
            for (int e = 0; e < 8; ++e) afrag[e] = (short)f2b(af[e]);
            #pragma unroll
            for (int nt = 0; nt < 4; ++nt) {
                int brow = nt * 16 + l15;
                u32 bb = (u32)(brow * 128 + ks * 64 + g * 16);
                bf16x8 bfrag = *(const bf16x8*)((const char*)wsm + (bb ^ ((brow & 7) << 4)));
                acc[nt] = __builtin_amdgcn_mfma_f32_16x16x32_bf16(afrag, bfrag, acc[nt], 0, 0, 0);
            }
        }
    }
    // epilogue: C col=l15(+16nt), row=g*4+r
    #pragma unroll
    for (int nt = 0; nt < 4; ++nt) {
        int dcol = nt * 16 + l15;
        #pragma unroll
        for (int r = 0; r < 4; ++r) {
            int row = row0 + w * 16 + g * 4 + r;
            float v = acc[nt][r];
            if (which == 0)      Qb[(size_t)row * DH + dcol] = f2b(v * 0.125f);
            else if (which == 1) Kb[(size_t)row * DH + dcol] = f2b(v);
            else { int bb2 = row >> 11, t = row & 2047;
                   Vt[(size_t)bb2 * DH * NT + (size_t)dcol * NT + t] = f2b(v); }
        }
    }
}

// ---------------------------------------------------------------------------
// Flash attention. Block = 4 waves x 16 q-rows (QBLK=64). Balanced KV
// chunking: block covers <= CHUNK KV tiles of q-block qb; partials merged.
// grid (sum_qb nchunks(qb), NB)
// ---------------------------------------------------------------------------
__global__ __launch_bounds__(256) void attn(
    const u16* __restrict__ Qb, const u16* __restrict__ Kb,
    const u16* __restrict__ Vt, u16* __restrict__ pO, float* __restrict__ pml,
    int CHUNK, int SLOTS)
{
    __shared__ u16 k_lds[4096];
    __shared__ u16 v_lds[4096];
    __shared__ u16 p_lds[4][16 * 72];

    const int tid = threadIdx.x, lane = tid & 63, w = tid >> 6;
    const int l15 = lane & 15, g = lane >> 4;
    const int b = blockIdx.y;

    // decode blockIdx.x -> (qb, chunk)
    int flat = blockIdx.x, qb = 0, nc;
    for (;;) { nc = (qb + CHUNK) / CHUNK; if (flat < nc) break; flat -= nc; ++qb; }
    const int chunk = flat;
    const int t0 = chunk * CHUNK;
    const int t1 = min(t0 + CHUNK, qb + 1);
    const int q0 = qb * 64;

    const u16* Qg = Qb + ((size_t)b * NT + q0 + w * 16) * DH;
    const u16* Kg = Kb + (size_t)b * NT * DH;
    const u16* Vg = Vt + (size_t)b * DH * NT;

    bf16x8 qf[2];
    qf[0] = *(const bf16x8*)(Qg + l15 * DH + g * 8);
    qf[1] = *(const bf16x8*)(Qg + l15 * DH + 32 + g * 8);

    float m_run[4], l_run[4];
    f32x4 oacc[4];
    #pragma unroll
    for (int r = 0; r < 4; ++r) { m_run[r] = -INFINITY; l_run[r] = 0.f; }
    #pragma unroll
    for (int nt = 0; nt < 4; ++nt) oacc[nt] = {0.f, 0.f, 0.f, 0.f};

    for (int t = t0; t < t1; ++t) {
        const int j0 = t * 64;
        __syncthreads();
        // stage K [j][d] and Vt [d][j] tiles via DMA, pre-swizzled source
        #pragma unroll
        for (int i = 0; i < 2; ++i) {
            u32 D = (u32)(w * 2048 + i * 1024 + lane * 16);
            u32 r = D >> 7, c = D & 127;
            u32 cs = c ^ ((r & 7) << 4);
            gld16(Kg + (size_t)(j0 + r) * DH + (cs >> 1), (char*)k_lds + w * 2048 + i * 1024);
            gld16(Vg + (size_t)r * NT + j0 + (cs >> 1),   (char*)v_lds + w * 2048 + i * 1024);
        }
        __syncthreads();

        // ---- QK^T ----
        f32x4 sacc[4];
        #pragma unroll
        for (int nt = 0; nt < 4; ++nt) sacc[nt] = {0.f, 0.f, 0.f, 0.f};
        __builtin_amdgcn_s_setprio(1);
        #pragma unroll
        for (int ks = 0; ks < 2; ++ks) {
            #pragma unroll
            for (int nt = 0; nt < 4; ++nt) {
                int brow = nt * 16 + l15;
                u32 bb = (u32)(brow * 128 + ks * 64 + g * 16);
                bf16x8 bf = *(const bf16x8*)((const char*)k_lds + (bb ^ ((brow & 7) << 4)));
                sacc[nt] = __builtin_amdgcn_mfma_f32_16x16x32_bf16(qf[ks], bf, sacc[nt], 0, 0, 0);
            }
        }
        __builtin_amdgcn_s_setprio(0);
        if (t == qb) {  // causal mask, diagonal tile only
            #pragma unroll
            for (int nt = 0; nt < 4; ++nt) {
                int j_local = nt * 16 + l15;
                #pragma unroll
                for (int r = 0; r < 4; ++r) {
                    int q_local = w * 16 + g * 4 + r;
                    if (j_local > q_local) sacc[nt][r] = -1e30f;
                }
            }
        }
        // ---- online softmax ----
        float p[4][4];
        #pragma unroll
        for (int r = 0; r < 4; ++r) {
            float mx = fmaxf(fmaxf(sacc[0][r], sacc[1][r]), fmaxf(sacc[2][r], sacc[3][r]));
            mx = fmaxf(mx, __shfl_xor(mx, 1));
            mx = fmaxf(mx, __shfl_xor(mx, 2));
            mx = fmaxf(mx, __shfl_xor(mx, 4));
            mx = fmaxf(mx, __shfl_xor(mx, 8));
            float m_new = fmaxf(m_run[r], mx);
            float alpha = __expf(m_run[r] - m_new);
            float ps = 0.f;
            #pragma unroll
            for (int nt = 0; nt < 4; ++nt) {
                float pv = __expf(sacc[nt][r] - m_new);
                p[nt][r] = pv; ps += pv;
            }
            ps += __shfl_xor(ps, 1); ps += __shfl_xor(ps, 2);
            ps += __shfl_xor(ps, 4); ps += __shfl_xor(ps, 8);
            l_run[r] = l_run[r] * alpha + ps;
            m_run[r] = m_new;
            #pragma unroll
            for (int nt = 0; nt < 4; ++nt) oacc[nt][r] *= alpha;
        }
        // ---- P -> per-wave LDS (stride 72), re-read in A layout ----
        u16* pw = p_lds[w];
        #pragma unroll
        for (int r = 0; r < 4; ++r) {
            int qrow = g * 4 + r;
            #pragma unroll
            for (int nt = 0; nt < 4; ++nt)
                pw[qrow * 72 + nt * 16 + l15] = f2b(p[nt][r]);
        }
        // ---- PV ----
        __builtin_amdgcn_s_setprio(1);
        #pragma unroll
        for (int ks = 0; ks < 2; ++ks) {
            bf16x8 pa = *(const bf16x8*)((const char*)pw + (l15 * 144 + ks * 64 + g * 16));
            #pragma unroll
            for (int nt = 0; nt < 4; ++nt) {
                int drow = nt * 16 + l15;
                u32 bb = (u32)(drow * 128 + ks * 64 + g * 16);
                bf16x8 vf = *(const bf16x8*)((const char*)v_lds + (bb ^ ((drow & 7) << 4)));
                oacc[nt] = __builtin_amdgcn_mfma_f32_16x16x32_bf16(pa, vf, oacc[nt], 0, 0, 0);
            }
        }
        __builtin_amdgcn_s_setprio(0);
    }

    const int slot = (b * 32 + qb) * SLOTS + chunk;
    u16* Op = pO + (size_t)slot * 4096;
    #pragma unroll
    for (int nt = 0; nt < 4; ++nt)
        #pragma unroll
        for (int r = 0; r < 4; ++r)
            Op[(w * 16 + g * 4 + r) * 64 + nt * 16 + l15] = f2b(oacc[nt][r]);
    if (l15 == 0) {
        float* mlp = pml + (size_t)slot * 128;
        #pragma unroll
        for (int r = 0; r < 4; ++r) {
            int row = w * 16 + g * 4 + r;
            mlp[row * 2]     = m_run[r];
            mlp[row * 2 + 1] = l_run[r];
        }
    }
}

// ---------------------------------------------------------------------------
// Merge <=SLOTS partials per q-row; fp32 output.
// ---------------------------------------------------------------------------
__global__ __launch_bounds__(256) void merge(
    const u16* __restrict__ pO, const float* __restrict__ pml,
    float* __restrict__ out, int CHUNK, int SLOTS)
{
    int idx = blockIdx.x * 256 + threadIdx.x;
    int row = idx >> 6, d = idx & 63;
    int b = row >> 11, q = row & 2047;
    int qb = q >> 6, rl = q & 63;
    int nc = (qb + CHUNK) / CHUNK;
    int base = (b * 32 + qb) * SLOTS;
    float m = -INFINITY;
    for (int c = 0; c < nc; ++c)
        m = fmaxf(m, pml[(size_t)(base + c) * 128 + rl * 2]);
    float osum = 0.f, lsum = 0.f;
    for (int c = 0; c < nc; ++c) {
        float mc = pml[(size_t)(base + c) * 128 + rl * 2];
        float lc = pml[(size_t)(base + c) * 128 + rl * 2 + 1];
        float wgt = __expf(mc - m);
        osum += wgt * b2f(pO[(size_t)(base + c) * 4096 + rl * 64 + d]);
        lsum += wgt * lc;
    }
    out[idx] = osum / lsum;
}

extern "C" void kernel_launch(void* const* d_in, const int* in_sizes, int n_in,
                              void* d_out, int out_size, void* d_ws, size_t ws_size,
                              hipStream_t stream) {
    const float* x  = (const float*)d_in[0];
    const float* WQ = (const float*)d_in[1];
    const float* WK = (const float*)d_in[2];
    const float* WV = (const float*)d_in[3];
    float* out = (float*)d_out;

    char* ws = (char*)d_ws;
    u16* Qb = (u16*)ws;                       // 1 MB
    u16* Kb = (u16*)(ws + 1048576);           // 1 MB
    u16* Vt = (u16*)(ws + 2097152);           // 1 MB
    u16* Wt = (u16*)(ws + 3145728);           // 384 KB (dead after qkv_gemm)
    // partials overlap Wt (attn runs after qkv_gemm on the same stream)
    int CHUNK, SLOTS;
    if (ws_size >= 7602176) { CHUNK = 8;  SLOTS = 4; }
    else                    { CHUNK = 16; SLOTS = 2; }
    u16*   pO  = (u16*)(ws + 3145728);
    float* pml = (float*)(ws + 3145728 + (size_t)NB * 32 * SLOTS * 4096 * 2);

    int gx = 0;
    for (int qb = 0; qb < 32; ++qb) gx += (qb + CHUNK) / CHUNK;  // 80 or 48

    wt_conv<<<dim3(16, 3), 256, 0, stream>>>(WQ, WK, WV, Wt);
    qkv_gemm<<<dim3(128, 3), 256, 0, stream>>>(x, Wt, Qb, Kb, Vt);
    attn<<<dim3(gx, NB), 256, 0, stream>>>(Qb, Kb, Vt, pO, pml, CHUNK, SLOTS);
    merge<<<2048, 256, 0, stream>>>(pO, pml, out, CHUNK, SLOTS);
}

// Round 4
// 48.086 us; speedup vs baseline: 9.5819x; 1.0861x over previous
//
#include <hip/hip_runtime.h>
#include <hip/hip_bf16.h>

#define NB 4
#define NT 2048
#define DM 1024
#define DH 64

typedef __attribute__((ext_vector_type(8))) short bf16x8;
typedef __attribute__((ext_vector_type(4))) float f32x4;
typedef unsigned short u16;
typedef unsigned int u32;

static __device__ __forceinline__ u16 f2b(float f) {
    __hip_bfloat16 h = __float2bfloat16(f);
    return __builtin_bit_cast(u16, h);
}
static __device__ __forceinline__ float b2f(u16 h) {
    return __builtin_bit_cast(float, (u32)h << 16);
}
// global -> LDS DMA, 16B per lane. lds ptr must be wave-uniform (HW adds lane*16).
static __device__ __forceinline__ void gld16(const void* g, void* l) {
    __builtin_amdgcn_global_load_lds((const __attribute__((address_space(1))) void*)g,
                                     (__attribute__((address_space(3))) void*)l, 16, 0, 0);
}

// ---------------------------------------------------------------------------
// Wt[which][d][k] bf16 <- W[k][d] fp32, via LDS transpose. grid (16, 3)
// ---------------------------------------------------------------------------
__global__ __launch_bounds__(256) void wt_conv(
    const float* __restrict__ WQ, const float* __restrict__ WK,
    const float* __restrict__ WV, u16* __restrict__ wt)
{
    __shared__ u16 tl[64][68];
    const int which = blockIdx.y, kt = blockIdx.x;
    const float* W = (which == 0) ? WQ : (which == 1) ? WK : WV;
    #pragma unroll
    for (int i = 0; i < 4; ++i) {
        int r = (threadIdx.x >> 4) + i * 16;         // k-local
        int c = (threadIdx.x & 15) * 4;              // d
        float4 v = *(const float4*)&W[(size_t)(kt * 64 + r) * DH + c];
        tl[r][c] = f2b(v.x); tl[r][c + 1] = f2b(v.y);
        tl[r][c + 2] = f2b(v.z); tl[r][c + 3] = f2b(v.w);
    }
    __syncthreads();
    int d = threadIdx.x >> 2, kc = (threadIdx.x & 3) * 16;
    u16 buf[16];
    #pragma unroll
    for (int j = 0; j < 16; ++j) buf[j] = tl[kc + j][d];
    u16* dst = wt + which * 65536 + d * 1024 + kt * 64 + kc;
    *(uint4*)dst = *(uint4*)&buf[0];
    *(uint4*)(dst + 8) = *(uint4*)&buf[8];
}

// ---------------------------------------------------------------------------
// QKV GEMM. grid (128, 3): 64-row tile x one of Q/K/V. 4 waves (16 rows each).
// Double-buffered: STAGE(next tile) -> compute(cur) -> barrier (T3 2-phase).
// x staged fp32 via global_load_lds (pre-swizzled src), bf16 cvt at frag build.
// ---------------------------------------------------------------------------
__global__ __launch_bounds__(256) void qkv_gemm(
    const float* __restrict__ x, const u16* __restrict__ wt,
    u16* __restrict__ Qb, u16* __restrict__ Kb, u16* __restrict__ Vt)
{
    __shared__ float xs[2][4096];     // 2 x 16 KB fp32, swizzle ^((r&7)<<5)
    __shared__ u16 wsm[2][4096];      // 2 x  8 KB bf16, swizzle ^((r&7)<<4)
    const int tid = threadIdx.x, lane = tid & 63, w = tid >> 6;
    const int l15 = lane & 15, g = lane >> 4;
    const int row0 = blockIdx.x * 64;
    const int which = blockIdx.y;
    const u16* Wg = wt + which * 65536;

    auto stage = [&](int kt, int bi) {
        #pragma unroll
        for (int i = 0; i < 4; ++i) {
            u32 D = (u32)(w * 4096 + i * 1024 + lane * 16);
            u32 r = D >> 8, c = D & 255;
            u32 cs = c ^ ((r & 7) << 5);
            gld16(x + (size_t)(row0 + r) * DM + kt * 64 + (cs >> 2),
                  (char*)&xs[bi][0] + w * 4096 + i * 1024);
        }
        #pragma unroll
        for (int i = 0; i < 2; ++i) {
            u32 D = (u32)(w * 2048 + i * 1024 + lane * 16);
            u32 r = D >> 7, c = D & 127;
            u32 cs = c ^ ((r & 7) << 4);
            gld16(Wg + (size_t)r * 1024 + kt * 64 + (cs >> 1),
                  (char*)&wsm[bi][0] + w * 2048 + i * 1024);
        }
    };

    f32x4 acc[4];
    #pragma unroll
    for (int i = 0; i < 4; ++i) acc[i] = {0.f, 0.f, 0.f, 0.f};

    stage(0, 0);
    __syncthreads();

    const int arow = w * 16 + l15;
    for (int kt = 0; kt < 16; ++kt) {
        const int cur = kt & 1;
        if (kt < 15) stage(kt + 1, cur ^ 1);      // in flight across compute
        const char* xb = (const char*)&xs[cur][0];
        const char* wb = (const char*)&wsm[cur][0];
        #pragma unroll
        for (int ks = 0; ks < 2; ++ks) {
            u32 abase = (u32)(arow * 256 + ks * 128 + g * 32);
            f32x4 a0 = *(const f32x4*)(xb + (abase ^ ((arow & 7) << 5)));
            f32x4 a1 = *(const f32x4*)(xb + ((abase + 16) ^ ((arow & 7) << 5)));
            bf16x8 afrag;
            #pragma unroll
            for (int e = 0; e < 4; ++e) afrag[e] = (short)f2b(a0[e]);
            #pragma unroll
            for (int e = 0; e < 4; ++e) afrag[4 + e] = (short)f2b(a1[e]);
            #pragma unroll
            for (int nt = 0; nt < 4; ++nt) {
                int brow = nt * 16 + l15;
                u32 bb = (u32)(brow * 128 + ks * 64 + g * 16);
                bf16x8 bfrag = *(const bf16x8*)(wb + (bb ^ ((brow & 7) << 4)));
                acc[nt] = __builtin_amdgcn_mfma_f32_16x16x32_bf16(afrag, bfrag, acc[nt], 0, 0, 0);
            }
        }
        __syncthreads();                          // drains DMA + guards reuse
    }
    // epilogue: C col=l15(+16nt), row=g*4+r
    #pragma unroll
    for (int nt = 0; nt < 4; ++nt) {
        int dcol = nt * 16 + l15;
        #pragma unroll
        for (int r = 0; r < 4; ++r) {
            int row = row0 + w * 16 + g * 4 + r;
            float v = acc[nt][r];
            if (which == 0)      Qb[(size_t)row * DH + dcol] = f2b(v * 0.125f);
            else if (which == 1) Kb[(size_t)row * DH + dcol] = f2b(v);
            else { int bb2 = row >> 11, t = row & 2047;
                   Vt[(size_t)bb2 * DH * NT + (size_t)dcol * NT + t] = f2b(v); }
        }
    }
}

// ---------------------------------------------------------------------------
// Flash attention, double-buffered K/V. Block = 4 waves x 16 q-rows (QBLK=64).
// Balanced KV chunking; partials merged. grid (sum_qb nchunks(qb), NB)
// ---------------------------------------------------------------------------
__global__ __launch_bounds__(256) void attn(
    const u16* __restrict__ Qb, const u16* __restrict__ Kb,
    const u16* __restrict__ Vt, u16* __restrict__ pO, float* __restrict__ pml,
    int CHUNK, int SLOTS)
{
    __shared__ u16 k_lds[2][4096];
    __shared__ u16 v_lds[2][4096];
    __shared__ u16 p_lds[4][16 * 72];

    const int tid = threadIdx.x, lane = tid & 63, w = tid >> 6;
    const int l15 = lane & 15, g = lane >> 4;
    const int b = blockIdx.y;

    // decode blockIdx.x -> (qb, chunk)
    int flat = blockIdx.x, qb = 0, nc;
    for (;;) { nc = (qb + CHUNK) / CHUNK; if (flat < nc) break; flat -= nc; ++qb; }
    const int chunk = flat;
    const int t0 = chunk * CHUNK;
    const int t1 = min(t0 + CHUNK, qb + 1);
    const int q0 = qb * 64;

    const u16* Qg = Qb + ((size_t)b * NT + q0 + w * 16) * DH;
    const u16* Kg = Kb + (size_t)b * NT * DH;
    const u16* Vg = Vt + (size_t)b * DH * NT;

    auto stage = [&](int t, int bi) {
        const int j0 = t * 64;
        #pragma unroll
        for (int i = 0; i < 2; ++i) {
            u32 D = (u32)(w * 2048 + i * 1024 + lane * 16);
            u32 r = D >> 7, c = D & 127;
            u32 cs = c ^ ((r & 7) << 4);
            gld16(Kg + (size_t)(j0 + r) * DH + (cs >> 1),
                  (char*)&k_lds[bi][0] + w * 2048 + i * 1024);
            gld16(Vg + (size_t)r * NT + j0 + (cs >> 1),
                  (char*)&v_lds[bi][0] + w * 2048 + i * 1024);
        }
    };

    stage(t0, 0);

    bf16x8 qf[2];
    qf[0] = *(const bf16x8*)(Qg + l15 * DH + g * 8);
    qf[1] = *(const bf16x8*)(Qg + l15 * DH + 32 + g * 8);

    float m_run[4], l_run[4];
    f32x4 oacc[4];
    #pragma unroll
    for (int r = 0; r < 4; ++r) { m_run[r] = -INFINITY; l_run[r] = 0.f; }
    #pragma unroll
    for (int nt = 0; nt < 4; ++nt) oacc[nt] = {0.f, 0.f, 0.f, 0.f};

    __syncthreads();

    for (int t = t0; t < t1; ++t) {
        const int cur = (t - t0) & 1;
        if (t + 1 < t1) stage(t + 1, cur ^ 1);    // in flight across compute
        const char* kb = (const char*)&k_lds[cur][0];
        const char* vb = (const char*)&v_lds[cur][0];

        // ---- QK^T ----
        f32x4 sacc[4];
        #pragma unroll
        for (int nt = 0; nt < 4; ++nt) sacc[nt] = {0.f, 0.f, 0.f, 0.f};
        __builtin_amdgcn_s_setprio(1);
        #pragma unroll
        for (int ks = 0; ks < 2; ++ks) {
            #pragma unroll
            for (int nt = 0; nt < 4; ++nt) {
                int brow = nt * 16 + l15;
                u32 bb = (u32)(brow * 128 + ks * 64 + g * 16);
                bf16x8 bf = *(const bf16x8*)(kb + (bb ^ ((brow & 7) << 4)));
                sacc[nt] = __builtin_amdgcn_mfma_f32_16x16x32_bf16(qf[ks], bf, sacc[nt], 0, 0, 0);
            }
        }
        __builtin_amdgcn_s_setprio(0);
        if (t == qb) {  // causal mask, diagonal tile only
            #pragma unroll
            for (int nt = 0; nt < 4; ++nt) {
                int j_local = nt * 16 + l15;
                #pragma unroll
                for (int r = 0; r < 4; ++r) {
                    int q_local = w * 16 + g * 4 + r;
                    if (j_local > q_local) sacc[nt][r] = -1e30f;
                }
            }
        }
        // ---- online softmax ----
        float p[4][4];
        #pragma unroll
        for (int r = 0; r < 4; ++r) {
            float mx = fmaxf(fmaxf(sacc[0][r], sacc[1][r]), fmaxf(sacc[2][r], sacc[3][r]));
            mx = fmaxf(mx, __shfl_xor(mx, 1));
            mx = fmaxf(mx, __shfl_xor(mx, 2));
            mx = fmaxf(mx, __shfl_xor(mx, 4));
            mx = fmaxf(mx, __shfl_xor(mx, 8));
            float m_new = fmaxf(m_run[r], mx);
            float alpha = __expf(m_run[r] - m_new);
            float ps = 0.f;
            #pragma unroll
            for (int nt = 0; nt < 4; ++nt) {
                float pv = __expf(sacc[nt][r] - m_new);
                p[nt][r] = pv; ps += pv;
            }
            ps += __shfl_xor(ps, 1); ps += __shfl_xor(ps, 2);
            ps += __shfl_xor(ps, 4); ps += __shfl_xor(ps, 8);
            l_run[r] = l_run[r] * alpha + ps;
            m_run[r] = m_new;
            #pragma unroll
            for (int nt = 0; nt < 4; ++nt) oacc[nt][r] *= alpha;
        }
        // ---- P -> per-wave LDS (stride 72), re-read in A layout ----
        u16* pw = p_lds[w];
        #pragma unroll
        for (int r = 0; r < 4; ++r) {
            int qrow = g * 4 + r;
            #pragma unroll
            for (int nt = 0; nt < 4; ++nt)
                pw[qrow * 72 + nt * 16 + l15] = f2b(p[nt][r]);
        }
        // ---- PV ----
        __builtin_amdgcn_s_setprio(1);
        #pragma unroll
        for (int ks = 0; ks < 2; ++ks) {
            bf16x8 pa = *(const bf16x8*)((const char*)pw + (l15 * 144 + ks * 64 + g * 16));
            #pragma unroll
            for (int nt = 0; nt < 4; ++nt) {
                int drow = nt * 16 + l15;
                u32 bb = (u32)(drow * 128 + ks * 64 + g * 16);
                bf16x8 vf = *(const bf16x8*)(vb + (bb ^ ((drow & 7) << 4)));
                oacc[nt] = __builtin_amdgcn_mfma_f32_16x16x32_bf16(pa, vf, oacc[nt], 0, 0, 0);
            }
        }
        __builtin_amdgcn_s_setprio(0);
        __syncthreads();                          // drains DMA + guards reuse
    }

    const int slot = (b * 32 + qb) * SLOTS + chunk;
    u16* Op = pO + (size_t)slot * 4096;
    #pragma unroll
    for (int nt = 0; nt < 4; ++nt)
        #pragma unroll
        for (int r = 0; r < 4; ++r)
            Op[(w * 16 + g * 4 + r) * 64 + nt * 16 + l15] = f2b(oacc[nt][r]);
    if (l15 == 0) {
        float* mlp = pml + (size_t)slot * 128;
        #pragma unroll
        for (int r = 0; r < 4; ++r) {
            int row = w * 16 + g * 4 + r;
            mlp[row * 2]     = m_run[r];
            mlp[row * 2 + 1] = l_run[r];
        }
    }
}

// ---------------------------------------------------------------------------
// Merge <=SLOTS partials per q-row; fp32 output.
// ---------------------------------------------------------------------------
__global__ __launch_bounds__(256) void merge(
    const u16* __restrict__ pO, const float* __restrict__ pml,
    float* __restrict__ out, int CHUNK, int SLOTS)
{
    int idx = blockIdx.x * 256 + threadIdx.x;
    int row = idx >> 6, d = idx & 63;
    int b = row >> 11, q = row & 2047;
    int qb = q >> 6, rl = q & 63;
    int nc = (qb + CHUNK) / CHUNK;
    int base = (b * 32 + qb) * SLOTS;
    float m = -INFINITY;
    for (int c = 0; c < nc; ++c)
        m = fmaxf(m, pml[(size_t)(base + c) * 128 + rl * 2]);
    float osum = 0.f, lsum = 0.f;
    for (int c = 0; c < nc; ++c) {
        float mc = pml[(size_t)(base + c) * 128 + rl * 2];
        float lc = pml[(size_t)(base + c) * 128 + rl * 2 + 1];
        float wgt = __expf(mc - m);
        osum += wgt * b2f(pO[(size_t)(base + c) * 4096 + rl * 64 + d]);
        lsum += wgt * lc;
    }
    out[idx] = osum / lsum;
}

extern "C" void kernel_launch(void* const* d_in, const int* in_sizes, int n_in,
                              void* d_out, int out_size, void* d_ws, size_t ws_size,
                              hipStream_t stream) {
    const float* x  = (const float*)d_in[0];
    const float* WQ = (const float*)d_in[1];
    const float* WK = (const float*)d_in[2];
    const float* WV = (const float*)d_in[3];
    float* out = (float*)d_out;

    char* ws = (char*)d_ws;
    u16* Qb = (u16*)ws;                       // 1 MB
    u16* Kb = (u16*)(ws + 1048576);           // 1 MB
    u16* Vt = (u16*)(ws + 2097152);           // 1 MB
    u16* Wt = (u16*)(ws + 3145728);           // 384 KB (dead after qkv_gemm)
    // partials overlap Wt (attn runs after qkv_gemm on the same stream)
    int CHUNK, SLOTS;
    if (ws_size >= 9830400) { CHUNK = 6;  SLOTS = 6; }   // 408 blocks, max 6 tiles
    else                    { CHUNK = 16; SLOTS = 2; }
    u16*   pO  = (u16*)(ws + 3145728);
    float* pml = (float*)(ws + 3145728 + (size_t)NB * 32 * SLOTS * 4096 * 2);

    int gx = 0;
    for (int qb = 0; qb < 32; ++qb) gx += (qb + CHUNK) / CHUNK;  // 102 or 48

    wt_conv<<<dim3(16, 3), 256, 0, stream>>>(WQ, WK, WV, Wt);
    qkv_gemm<<<dim3(128, 3), 256, 0, stream>>>(x, Wt, Qb, Kb, Vt);
    attn<<<dim3(gx, NB), 256, 0, stream>>>(Qb, Kb, Vt, pO, pml, CHUNK, SLOTS);
    merge<<<2048, 256, 0, stream>>>(pO, pml, out, CHUNK, SLOTS);
}